// Round 5
// baseline (210.259 us; speedup 1.0000x reference)
//
#include <hip/hip_runtime.h>

#define HW     262144          // 512*512
#define CHW    786432          // 3*HW
#define NBINS  256
#define PBB    16              // chunks (blocks) per batch
#define CHUNK  (HW / PBB)      // 16384 elements per block

#define AGENT __HIP_MEMORY_SCOPE_AGENT

__device__ __forceinline__ unsigned int aload_u32(const unsigned int* p) {
    return __hip_atomic_load(p, __ATOMIC_RELAXED, AGENT);
}
__device__ __forceinline__ void astore_u32(unsigned int* p, unsigned int v) {
    __hip_atomic_store(p, v, __ATOMIC_RELAXED, AGENT);
}
__device__ __forceinline__ float aload_f32(const float* p) {
    return __hip_atomic_load(p, __ATOMIC_RELAXED, AGENT);
}
__device__ __forceinline__ void astore_f32(float* p, float v) {
    __hip_atomic_store(p, v, __ATOMIC_RELAXED, AGENT);
}

// One kernel does everything via ticket gating:
//  - 1024 blocks make per-chunk histograms -> part[]
//  - last block per batch (ticket1) computes layer 1 -> h1pre[]
//  - last batch-finisher (ticket2) runs BN1+L2+BN2+L3 -> out
// Non-survivors EXIT (no spin) -> no co-residency requirement, no deadlock.
__global__ __launch_bounds__(256, 4) void fused_all(
    const float* __restrict__ x,
    const float* __restrict__ W1, const float* __restrict__ b1,
    const float* __restrict__ g1, const float* __restrict__ be1,
    const float* __restrict__ W2, const float* __restrict__ b2,
    const float* __restrict__ g2, const float* __restrict__ be2,
    const float* __restrict__ W3, const float* __restrict__ b3,
    unsigned int* __restrict__ ticket1, unsigned int* __restrict__ ticket2,
    unsigned int* __restrict__ part, float* __restrict__ h1pre,
    float* __restrict__ out)
{
    __shared__ __align__(16) char smem[34816];
    int* bc = (int*)(smem + 34560);
    const int tid = threadIdx.x;
    const int g   = blockIdx.x;
    const int b   = g >> 4;           // batch
    const int p   = g & 15;           // chunk within batch

    // ================= Phase 1: chunk histogram =================
    {
        unsigned int* lh = (unsigned int*)smem;        // 8192 u32 = 32 KB
        for (int i = tid; i < NBINS * 32; i += 256) lh[i] = 0u;
        __syncthreads();

        const int col = tid & 31;                      // bank-exclusive column
        const float4* src = (const float4*)(x + (size_t)b * CHW + (size_t)p * CHUNK);

        float4 buf[4];
#pragma unroll
        for (int q = 0; q < 4; ++q) buf[q] = src[tid + q * 256];

        for (int grp = 0; grp < 4; ++grp) {
            float4 nxt[4];
            if (grp < 3) {
#pragma unroll
                for (int q = 0; q < 4; ++q) nxt[q] = src[tid + (grp + 1) * 1024 + q * 256];
            }
#pragma unroll
            for (int q = 0; q < 4; ++q) {
                float vv[4] = {buf[q].x, buf[q].y, buf[q].z, buf[q].w};
#pragma unroll
                for (int j = 0; j < 4; ++j) {
                    // input is uniform [0,1): trunc == floor, always in-range
                    int idx = (int)(vv[j] * 256.0f);
                    idx = idx < 0 ? 0 : (idx > 255 ? 255 : idx);
                    atomicAdd(&lh[idx * 32 + col], 1u);
                }
            }
#pragma unroll
            for (int q = 0; q < 4; ++q) buf[q] = nxt[q];
        }
        __syncthreads();

        // column-reduce with rotation: lanes l, l+32 share a bank (2-way = free)
        unsigned int s = 0;
#pragma unroll
        for (int i = 0; i < 32; ++i) s += lh[tid * 32 + ((tid + i) & 31)];
        astore_u32(&part[(size_t)g * NBINS + tid], s);
    }

    // ================= ticket 1: last chunk of this batch survives =================
    __syncthreads();                   // drains vmcnt before barrier (store visibility)
    if (tid == 0) {
        __threadfence();               // release: part[] -> device scope
        unsigned int old = __hip_atomic_fetch_add(&ticket1[b], 1u,
                                                  __ATOMIC_ACQ_REL, AGENT);
        *bc = (old == (PBB - 1)) ? 1 : 0;
    }
    __syncthreads();
    if (!*bc) return;
    __threadfence();                   // acquire: invalidate stale cache

    // ================= Phase 2: layer 1 for batch b =================
    {
        float* row  = (float*)smem;                    // 256 f32
        float* sred = (float*)(smem + 1024);           // 4 f32
        __syncthreads();

        unsigned int s = 0;
        const unsigned int* pp = part + (size_t)b * PBB * NBINS + tid;
#pragma unroll
        for (int q = 0; q < PBB; ++q) s += aload_u32(pp + q * NBINS);
        row[tid] = (float)s;
        __syncthreads();

        float ssum = row[tid];
#pragma unroll
        for (int off = 32; off > 0; off >>= 1) ssum += __shfl_xor(ssum, off);
        if ((tid & 63) == 0) sred[tid >> 6] = ssum;
        __syncthreads();
        const float S   = sred[0] + sred[1] + sred[2] + sred[3];
        const float inv = 1.0f / (S + 1e-6f);

        if (tid < 128) {
            const float4* w4 = (const float4*)(W1 + (size_t)tid * NBINS);
            float a0 = 0.f, a1 = 0.f, a2 = 0.f, a3 = 0.f;
#pragma unroll
            for (int k4 = 0; k4 < 64; ++k4) {
                float4 wv = w4[k4];
                float4 rv = *(const float4*)&row[k4 * 4];
                a0 += wv.x * rv.x; a1 += wv.y * rv.y;
                a2 += wv.z * rv.z; a3 += wv.w * rv.w;
            }
            astore_f32(&h1pre[b * 128 + tid],
                       ((a0 + a1) + (a2 + a3)) * inv + b1[tid]);
        }
    }

    // ================= ticket 2: last batch-finisher survives =================
    __syncthreads();
    if (tid == 0) {
        __threadfence();
        unsigned int old = __hip_atomic_fetch_add(ticket2, 1u,
                                                  __ATOMIC_ACQ_REL, AGENT);
        *bc = (old == 63) ? 1 : 0;
    }
    __syncthreads();
    if (!*bc) return;
    __threadfence();

    // ================= Phase 3: BN1+ReLU -> L2 -> BN2+ReLU -> L3 =================
    {
        float*  pd  = (float*)smem;                    // 2*4096 f32 = 32 KB
        float2* ss1 = (float2*)(smem + 32768);         // 128 float2
        float2* ss2 = (float2*)(smem + 33792);         // 64 float2
        __syncthreads();

        const int w    = tid >> 6;                     // wave 0..3
        const int lane = tid & 63;                     // batch = lane
        const int h    = w & 1;                        // k-half of 128 features
        const int jg   = w >> 1;                       // j-group (32 wide)

        // 3a: this lane's batch-row half (agent loads: cross-XCD safety)
        float r[64];
        {
            const float* hp = h1pre + lane * 128 + h * 64;
#pragma unroll
            for (int k = 0; k < 64; ++k) r[k] = aload_f32(hp + k);
        }

        // 3b: BN1 stats — wave w owns f = h*64 + jg*32 + i (disjoint cover)
#pragma unroll
        for (int i = 0; i < 32; ++i) {
            const int idx = jg * 32 + i;
            float v = r[idx];
            float s = v, q = v * v;
#pragma unroll
            for (int off = 32; off > 0; off >>= 1) {
                s += __shfl_xor(s, off);
                q += __shfl_xor(q, off);
            }
            const float mu  = s * (1.0f / 64.0f);
            const float var = q * (1.0f / 64.0f) - mu * mu;
            const int   f   = h * 64 + idx;
            const float sc  = g1[f] * rsqrtf(var + 1e-5f);
            if (lane == 0) ss1[f] = make_float2(sc, be1[f] - mu * sc);
        }
        __syncthreads();

        // 3c: normalize + ReLU in registers
#pragma unroll
        for (int k = 0; k < 64; ++k) {
            float2 s2 = ss1[h * 64 + k];
            r[k] = fmaxf(r[k] * s2.x + s2.y, 0.0f);
        }

        // 3d: layer-2 half-dot partials; wave w -> j in [jg*32, +32), half h
        {
            float* pdh = pd + h * 4096;
            for (int jj = 0; jj < 32; ++jj) {
                const int j = jg * 32 + jj;
                const float* w2 = W2 + (size_t)j * 128 + h * 64;
                float a0 = 0.f, a1 = 0.f, a2 = 0.f, a3 = 0.f;
#pragma unroll
                for (int k = 0; k < 64; k += 4) {
                    a0 += r[k+0] * w2[k+0]; a1 += r[k+1] * w2[k+1];
                    a2 += r[k+2] * w2[k+2]; a3 += r[k+3] * w2[k+3];
                }
                pdh[j * 64 + lane] = (a0 + a1) + (a2 + a3);
            }
        }
        __syncthreads();

        // 3e: combine halves + bias
        for (int i = tid; i < 4096; i += 256) {
            pd[i] = pd[i] + pd[4096 + i] + b2[i >> 6];
        }
        __syncthreads();

        // 3f: BN2 stats — wave w owns j in [w*16, +16)
#pragma unroll
        for (int i = 0; i < 16; ++i) {
            const int j = w * 16 + i;
            float v = pd[j * 64 + lane];
            float s = v, q = v * v;
#pragma unroll
            for (int off = 32; off > 0; off >>= 1) {
                s += __shfl_xor(s, off);
                q += __shfl_xor(q, off);
            }
            const float mu  = s * (1.0f / 64.0f);
            const float var = q * (1.0f / 64.0f) - mu * mu;
            const float sc  = g2[j] * rsqrtf(var + 1e-5f);
            if (lane == 0) ss2[j] = make_float2(sc, be2[j] - mu * sc);
        }
        __syncthreads();

        // 3g: normalize + ReLU + layer 3
        if (tid < 64) {
            float acc = b3[0];
#pragma unroll
            for (int j = 0; j < 64; ++j) {
                float2 s2 = ss2[j];
                acc += fmaxf(pd[j * 64 + tid] * s2.x + s2.y, 0.0f) * W3[j];
            }
            out[tid] = acc;
        }
    }
}

extern "C" void kernel_launch(void* const* d_in, const int* in_sizes, int n_in,
                              void* d_out, int out_size, void* d_ws, size_t ws_size,
                              hipStream_t stream) {
    const float* x   = (const float*)d_in[0];
    const float* W1  = (const float*)d_in[1];
    const float* b1  = (const float*)d_in[2];
    const float* g1  = (const float*)d_in[3];
    const float* be1 = (const float*)d_in[4];
    const float* W2  = (const float*)d_in[5];
    const float* b2  = (const float*)d_in[6];
    const float* g2  = (const float*)d_in[7];
    const float* be2 = (const float*)d_in[8];
    const float* W3  = (const float*)d_in[9];
    const float* b3  = (const float*)d_in[10];
    float* out = (float*)d_out;

    // ws layout: [0,256) ticket1 (64 u32), [256,260) ticket2, part @4KB (1MB),
    // h1pre @ 4KB+1MB (32KB)
    unsigned int* ticket1 = (unsigned int*)d_ws;
    unsigned int* ticket2 = (unsigned int*)((char*)d_ws + 256);
    unsigned int* part    = (unsigned int*)((char*)d_ws + 4096);
    float*        h1pre   = (float*)((char*)d_ws + 4096 + (1u << 20));

    hipMemsetAsync(d_ws, 0, 512, stream);   // zero tickets every call (replay-safe)

    hipLaunchKernelGGL(fused_all, dim3(64 * PBB), dim3(256), 0, stream,
                       x, W1, b1, g1, be1, W2, b2, g2, be2, W3, b3,
                       ticket1, ticket2, part, h1pre, out);
}

// Round 6
// 103.945 us; speedup vs baseline: 2.0228x; 2.0228x over previous
//
#include <hip/hip_runtime.h>

#define HW     262144          // 512*512
#define CHW    786432          // 3*HW
#define NBINS  256
#define PBB    4               // hist blocks per batch
#define CHUNK  (HW / PBB)      // 65536 elements per block

// ---------------- Node 1: partial histogram + W1 projection ----------------
// 256 blocks (64 batches x 4 chunks) x 512 threads. Each block:
//  - bank-exclusive LDS histogram of its 64K-element chunk (channel 0)
//  - projects its PARTIAL counts through W1 (linear => partials sum later)
//  - writes proj[g][0:128] and S_part[g]. No atomics, no fences.
__global__ __launch_bounds__(512, 1) void hist_proj_kernel(
    const float* __restrict__ x, const float* __restrict__ W1,
    float* __restrict__ proj, float* __restrict__ S_part)
{
    __shared__ unsigned int lh[NBINS * 32];     // 32 KB, bank-exclusive cols
    __shared__ float row[NBINS];
    __shared__ float projL[128];
    __shared__ float sred[4];

    const int tid = threadIdx.x;
    for (int i = tid; i < NBINS * 32; i += 512) lh[i] = 0u;
    __syncthreads();

    const int g = blockIdx.x;
    const int b = g >> 2;
    const int p = g & 3;
    const float4* src = (const float4*)(x + (size_t)b * CHW + (size_t)p * CHUNK);
    const int col = tid & 31;                   // bank == lane%32

    float4 buf[4];
#pragma unroll
    for (int q = 0; q < 4; ++q) buf[q] = src[tid + q * 512];
    for (int grp = 0; grp < 8; ++grp) {
        float4 nxt[4];
        if (grp < 7) {
#pragma unroll
            for (int q = 0; q < 4; ++q) nxt[q] = src[tid + (grp + 1) * 2048 + q * 512];
        }
#pragma unroll
        for (int q = 0; q < 4; ++q) {
            float vv[4] = {buf[q].x, buf[q].y, buf[q].z, buf[q].w};
#pragma unroll
            for (int j = 0; j < 4; ++j) {
                float f = vv[j];
                int idx = (int)(f * 256.0f);    // f>=0 guarded => trunc == floor
                idx = idx > 255 ? 255 : idx;    // f==1.0 -> 255 (matches clip)
                if (f >= 0.0f && f <= 1.0f) atomicAdd(&lh[idx * 32 + col], 1u);
            }
        }
#pragma unroll
        for (int q = 0; q < 4; ++q) buf[q] = nxt[q];
    }
    __syncthreads();

    // column-reduce (rotation keeps 2 lanes/bank = free) + partial count sum
    if (tid < 256) {
        unsigned int s = 0;
#pragma unroll
        for (int i = 0; i < 32; ++i) s += lh[tid * 32 + ((tid + i) & 31)];
        float sf = (float)s;
        row[tid] = sf;
#pragma unroll
        for (int off = 32; off > 0; off >>= 1) sf += __shfl_xor(sf, off);
        if ((tid & 63) == 0) sred[tid >> 6] = sf;
    }
    __syncthreads();

    // projection: wave w owns j in [w*16, +16); W1 reads coalesced (lane = k)
    {
        const int w = tid >> 6, lane = tid & 63;
        for (int jj = 0; jj < 16; ++jj) {
            const int j = w * 16 + jj;
            const float* wr = W1 + (size_t)j * NBINS;
            float a = 0.f;
#pragma unroll
            for (int c = 0; c < 4; ++c) a += wr[c * 64 + lane] * row[c * 64 + lane];
#pragma unroll
            for (int off = 32; off > 0; off >>= 1) a += __shfl_xor(a, off);
            if (lane == 0) projL[j] = a;
        }
    }
    __syncthreads();

    if (tid < 32) ((float4*)(proj + (size_t)g * 128))[tid] = ((const float4*)projL)[tid];
    if (tid == 0) S_part[g] = sred[0] + sred[1] + sred[2] + sred[3];
}

// ---------------- Node 2: combine + BN1+ReLU -> L2 -> BN2+ReLU -> L3 ----------------
#define H1S 129   // pad: bank = (129*lane + k)%32 = (lane+k)%32 -> conflict-free columns
__global__ __launch_bounds__(1024, 1) void tail_kernel(
    const float* __restrict__ proj, const float* __restrict__ S_part,
    const float* __restrict__ b1, const float* __restrict__ g1, const float* __restrict__ be1,
    const float* __restrict__ W2, const float* __restrict__ b2,
    const float* __restrict__ g2, const float* __restrict__ be2,
    const float* __restrict__ W3, const float* __restrict__ b3,
    float* __restrict__ out)
{
    __shared__ float  h1L[64 * H1S];    // 33 KB
    __shared__ float  pd[2 * 4096];     // 32 KB
    __shared__ float2 ss1[128];
    __shared__ float2 ss2[64];
    const int tid = threadIdx.x;

    // A: combine 4 proj partials per (b,j), normalize, +b1 -> h1L (pre-BN)
#pragma unroll
    for (int o = 0; o < 8; ++o) {
        const int idx = o * 1024 + tid;
        const int b = idx >> 7, j = idx & 127;
        const float* pp = proj + b * 512 + j;
        const float raw = (pp[0] + pp[128]) + (pp[256] + pp[384]);
        const float* sp = S_part + b * 4;
        const float S   = (sp[0] + sp[1]) + (sp[2] + sp[3]);
        h1L[b * H1S + j] = raw * (1.0f / (S + 1e-6f)) + b1[j];
    }
    __syncthreads();

    const int w    = tid >> 6;          // wave 0..15
    const int lane = tid & 63;          // batch = lane
    const int h    = w & 1;             // k-half of the 128 features
    const int jg   = w >> 1;            // group 0..7

    // B: this lane's batch-row half into registers (2 lanes/bank = free)
    float r[64];
#pragma unroll
    for (int k = 0; k < 64; ++k) r[k] = h1L[lane * H1S + h * 64 + k];

    // C: BN1 stats — wave owns f = h*64 + jg*8 + i (disjoint cover of 128)
#pragma unroll
    for (int i = 0; i < 8; ++i) {
        const int kl = jg * 8 + i;
        float v = r[kl];
        float s = v, q = v * v;
#pragma unroll
        for (int off = 32; off > 0; off >>= 1) {
            s += __shfl_xor(s, off);
            q += __shfl_xor(q, off);
        }
        const float mu  = s * (1.0f / 64.0f);
        const float var = q * (1.0f / 64.0f) - mu * mu;
        const int   f   = h * 64 + kl;
        const float sc  = g1[f] * rsqrtf(var + 1e-5f);
        if (lane == 0) ss1[f] = make_float2(sc, be1[f] - mu * sc);
    }
    __syncthreads();

    // D: normalize + ReLU in registers
#pragma unroll
    for (int k = 0; k < 64; ++k) {
        float2 s2 = ss1[h * 64 + k];
        r[k] = fmaxf(r[k] * s2.x + s2.y, 0.0f);
    }

    // E: layer-2 half-dot partials; wave w -> j in [jg*8,+8), half h
    {
        float* pdh = pd + h * 4096;
        for (int jj = 0; jj < 8; ++jj) {
            const int j = jg * 8 + jj;
            const float* w2 = W2 + (size_t)j * 128 + h * 64;  // wave-uniform loads
            float a0 = 0.f, a1 = 0.f, a2 = 0.f, a3 = 0.f;
#pragma unroll
            for (int k = 0; k < 64; k += 4) {
                a0 += r[k+0] * w2[k+0]; a1 += r[k+1] * w2[k+1];
                a2 += r[k+2] * w2[k+2]; a3 += r[k+3] * w2[k+3];
            }
            pdh[j * 64 + lane] = (a0 + a1) + (a2 + a3);
        }
    }
    __syncthreads();

    // F: combine halves + bias
    for (int i = tid; i < 4096; i += 1024) pd[i] = pd[i] + pd[4096 + i] + b2[i >> 6];
    __syncthreads();

    // G: BN2 stats — wave owns j in [w*4, +4)
#pragma unroll
    for (int i = 0; i < 4; ++i) {
        const int j = w * 4 + i;
        float v = pd[j * 64 + lane];
        float s = v, q = v * v;
#pragma unroll
        for (int off = 32; off > 0; off >>= 1) {
            s += __shfl_xor(s, off);
            q += __shfl_xor(q, off);
        }
        const float mu  = s * (1.0f / 64.0f);
        const float var = q * (1.0f / 64.0f) - mu * mu;
        const float sc  = g2[j] * rsqrtf(var + 1e-5f);
        if (lane == 0) ss2[j] = make_float2(sc, be2[j] - mu * sc);
    }
    __syncthreads();

    // H: normalize + ReLU + layer 3
    if (tid < 64) {
        float acc = b3[0];
#pragma unroll
        for (int j = 0; j < 64; ++j) {
            float2 s2 = ss2[j];
            acc += fmaxf(pd[j * 64 + tid] * s2.x + s2.y, 0.0f) * W3[j];
        }
        out[tid] = acc;
    }
}

extern "C" void kernel_launch(void* const* d_in, const int* in_sizes, int n_in,
                              void* d_out, int out_size, void* d_ws, size_t ws_size,
                              hipStream_t stream) {
    const float* x   = (const float*)d_in[0];
    const float* W1  = (const float*)d_in[1];
    const float* b1  = (const float*)d_in[2];
    const float* g1  = (const float*)d_in[3];
    const float* be1 = (const float*)d_in[4];
    const float* W2  = (const float*)d_in[5];
    const float* b2  = (const float*)d_in[6];
    const float* g2  = (const float*)d_in[7];
    const float* be2 = (const float*)d_in[8];
    const float* W3  = (const float*)d_in[9];
    const float* b3  = (const float*)d_in[10];
    float* out = (float*)d_out;

    // ws: proj[256][128] f32 @0 (128 KB), S_part[256] @128KB — fully
    // overwritten every call before being read (poison-safe, replay-safe).
    float* proj   = (float*)d_ws;
    float* S_part = (float*)((char*)d_ws + 131072);

    hipLaunchKernelGGL(hist_proj_kernel, dim3(64 * PBB), dim3(512), 0, stream,
                       x, W1, proj, S_part);
    hipLaunchKernelGGL(tail_kernel, dim3(1), dim3(1024), 0, stream,
                       proj, S_part, b1, g1, be1, W2, b2, g2, be2, W3, b3, out);
}